// Round 4
// baseline (14.750 us; speedup 1.0000x reference)
//
#include <hip/hip_runtime.h>
#include <math.h>

#define BB 1024
#define DD 128
#define TILE 64
#define NBLK 256  // (BB/TILE)^2 blocks

constexpr float EPSF = 1e-6f;
constexpr float MARGINF = 1.0f;
constexpr float INV_COUNT = 1.0f / (float)((BB - 1) * BB);  // 1/1047552

typedef __attribute__((ext_vector_type(8))) short bf16x8;
typedef __attribute__((ext_vector_type(4))) float f32x4;

union F4 { float4 v; float f[4]; };

__device__ __forceinline__ short f2bf(float f) {
    // native cast -> compiler emits paired v_cvt_pk_bf16_f32 (RNE), ~2 floats/inst
    return __builtin_bit_cast(short, (__bf16)f);
}

// One block per 64x64 output tile; 512 threads = 8 waves (2 row-groups x 4
// col-groups). A/B tiles staged in LDS as bf16 in MFMA-fragment order:
//   bucket = (row>>4)*4 + (k>>5)   (16 buckets x 1KB)
//   slot   = ((k>>3)&3)*16 + (row&15)  == the MFMA lane that consumes it
//   j      = k&7 (contiguous 16B per lane -> one ds_read_b128)
// Slots XOR-swizzled by (bucket&7) to kill staging write conflicts.
__global__ __launch_bounds__(512) void triplet_one_k(const float* __restrict__ a,
                                                     const float* __restrict__ b,
                                                     float* __restrict__ partials,
                                                     unsigned int* __restrict__ cnt,
                                                     float* __restrict__ out) {
    __shared__ __align__(16) ushort A_s[16 * 512];  // 16 KB
    __shared__ __align__(16) ushort B_s[16 * 512];  // 16 KB
    __shared__ float ta_s[TILE], tb_s[TILE], dap_s[TILE];
    __shared__ float wsum_s[8];
    __shared__ int last_s;

    const int tid = threadIdx.x;
    const int bidx = (int)blockIdx.x, bidy = (int)blockIdx.y;
    const int j0 = bidy * TILE;
    const int k0 = bidx * TILE;

    // ---------- Phase 1: coalesced loads + exact-fp32 stats + bf16 staging ----
    const int r    = tid >> 3;  // 0..63 local row
    const int part = tid & 7;   // 64B segment within the 512B row
    const float4* pa  = reinterpret_cast<const float4*>(a + (size_t)(j0 + r) * DD + part * 16);
    const float4* pbj = reinterpret_cast<const float4*>(b + (size_t)(j0 + r) * DD + part * 16);
    const float4* pbk = reinterpret_cast<const float4*>(b + (size_t)(k0 + r) * DD + part * 16);

    F4 av[4], bjv[4], bkv[4];
#pragma unroll
    for (int i = 0; i < 4; ++i) av[i].v = pa[i];
#pragma unroll
    for (int i = 0; i < 4; ++i) bjv[i].v = pbj[i];
#pragma unroll
    for (int i = 0; i < 4; ++i) bkv[i].v = pbk[i];

    float sa2 = 0.f, sa = 0.f, sap = 0.f, sb2 = 0.f, sb = 0.f;
#pragma unroll
    for (int i = 0; i < 4; ++i)
#pragma unroll
        for (int c = 0; c < 4; ++c) {
            const float x = av[i].f[c], yj = bjv[i].f[c], yk = bkv[i].f[c];
            sa2 = fmaf(x, x, sa2);
            sa += x;
            const float d = x - yj + EPSF;
            sap = fmaf(d, d, sap);
            sb2 = fmaf(yk, yk, sb2);
            sb += yk;
        }
#pragma unroll
    for (int off = 1; off <= 4; off <<= 1) {  // reduce 8-lane row groups
        sa2 += __shfl_xor(sa2, off);
        sa  += __shfl_xor(sa,  off);
        sap += __shfl_xor(sap, off);
        sb2 += __shfl_xor(sb2, off);
        sb  += __shfl_xor(sb,  off);
    }
    if (part == 0) {
        ta_s[r]  = fmaf(2.f * EPSF, sa, sa2);
        tb_s[r]  = fmaf(-2.f * EPSF, sb, sb2);
        dap_s[r] = sqrtf(sap);
    }

    // staging: this thread's 16 a-elems (k = part*16..part*16+15) form exactly
    // two 8-elem lane-fragments of one bucket; same for bk.
    {
        const int bucket = (r >> 4) * 4 + (part >> 1);
        const int g = bucket & 7;
        const int slot0 = (part & 1) * 32 + (r & 15);  // lk0*16 + lr
        const int s0 = slot0 ^ g;
        const int s1 = (slot0 + 16) ^ g;
        bf16x8 w0, w1, x0, x1;
#pragma unroll
        for (int c = 0; c < 4; ++c) {
            w0[c] = f2bf(av[0].f[c]);  w0[4 + c] = f2bf(av[1].f[c]);
            w1[c] = f2bf(av[2].f[c]);  w1[4 + c] = f2bf(av[3].f[c]);
            x0[c] = f2bf(bkv[0].f[c]); x0[4 + c] = f2bf(bkv[1].f[c]);
            x1[c] = f2bf(bkv[2].f[c]); x1[4 + c] = f2bf(bkv[3].f[c]);
        }
        *reinterpret_cast<bf16x8*>(&A_s[bucket * 512 + s0 * 8]) = w0;
        *reinterpret_cast<bf16x8*>(&A_s[bucket * 512 + s1 * 8]) = w1;
        *reinterpret_cast<bf16x8*>(&B_s[bucket * 512 + s0 * 8]) = x0;
        *reinterpret_cast<bf16x8*>(&B_s[bucket * 512 + s1 * 8]) = x1;
    }
    __syncthreads();

    // ---------- Phase 2: MFMA over conflict-free lane-linear fragments -------
    const int w = tid >> 6, lane = tid & 63;
    const int wr = w >> 2;  // 0..1 : 32-row group
    const int wc = w & 3;   // 0..3 : 16-col group

    f32x4 acc0 = {0.f, 0.f, 0.f, 0.f}, acc1 = {0.f, 0.f, 0.f, 0.f};
#pragma unroll
    for (int kc = 0; kc < 4; ++kc) {
        const int bA0 = (2 * wr) * 4 + kc;
        const int bA1 = (2 * wr + 1) * 4 + kc;
        const int bB  = wc * 4 + kc;
        const bf16x8 fa0 = *reinterpret_cast<const bf16x8*>(&A_s[bA0 * 512 + (lane ^ (bA0 & 7)) * 8]);
        const bf16x8 fa1 = *reinterpret_cast<const bf16x8*>(&A_s[bA1 * 512 + (lane ^ (bA1 & 7)) * 8]);
        const bf16x8 fb  = *reinterpret_cast<const bf16x8*>(&B_s[bB * 512 + (lane ^ (bB & 7)) * 8]);
        acc0 = __builtin_amdgcn_mfma_f32_16x16x32_bf16(fa0, fb, acc0, 0, 0, 0);
        acc1 = __builtin_amdgcn_mfma_f32_16x16x32_bf16(fa1, fb, acc1, 0, 0, 0);
    }

    // ---------- Phase 3: fused epilogue ----------
    const float Ceps = (float)DD * EPSF * EPSF;
    const int colL = wc * 16 + (lane & 15);
    const int col  = k0 + colL;
    const float tb = tb_s[colL];
    float local = 0.f;
#pragma unroll
    for (int m = 0; m < 2; ++m) {
        const f32x4 acc = m ? acc1 : acc0;
#pragma unroll
        for (int reg = 0; reg < 4; ++reg) {
            const int rowL = wr * 32 + m * 16 + (lane >> 4) * 4 + reg;
            const int row  = j0 + rowL;
            const float d2 = ta_s[rowL] + tb + Ceps - 2.f * acc[reg];
            const float dn = sqrtf(fmaxf(d2, 0.f));
            if (row != col) local += fmaxf(dap_s[rowL] - dn + MARGINF, 0.f);
        }
    }

    // ---------- Phase 4: block reduce + last-block-done finalize ----------
#pragma unroll
    for (int off = 32; off >= 1; off >>= 1) local += __shfl_xor(local, off);
    if (lane == 0) wsum_s[w] = local;
    __syncthreads();
    if (tid == 0) {
        float s = 0.f;
#pragma unroll
        for (int i = 0; i < 8; ++i) s += wsum_s[i];
        partials[bidy * 16 + bidx] = s;
        __threadfence();  // publish partial before signaling
        const unsigned int old = atomicAdd(cnt, 1u);
        last_s = (((old + 1u) & (NBLK - 1u)) == 0u) ? 1 : 0;  // start-value independent
    }
    __syncthreads();
    if (last_s) {
        float v = 0.f;
        if (tid < NBLK)  // cache-bypassing device-scope load (writers fenced above)
            v = __hip_atomic_load(&partials[tid], __ATOMIC_RELAXED, __HIP_MEMORY_SCOPE_AGENT);
#pragma unroll
        for (int off = 32; off >= 1; off >>= 1) v += __shfl_xor(v, off);
        if ((tid & 63) == 0) wsum_s[tid >> 6] = v;
        __syncthreads();
        if (tid == 0) {
            float t = 0.f;
#pragma unroll
            for (int i = 0; i < 8; ++i) t += wsum_s[i];
            out[0] = t * INV_COUNT;
        }
    }
}

extern "C" void kernel_launch(void* const* d_in, const int* in_sizes, int n_in,
                              void* d_out, int out_size, void* d_ws, size_t ws_size,
                              hipStream_t stream) {
    const float* a = (const float*)d_in[0];
    const float* b = (const float*)d_in[1];
    float* partials   = (float*)d_ws;                 // 256 floats
    unsigned int* cnt = (unsigned int*)d_ws + NBLK;   // 1 uint, past the partials
    float* out        = (float*)d_out;

    dim3 grid(BB / TILE, BB / TILE);
    triplet_one_k<<<grid, 512, 0, stream>>>(a, b, partials, cnt, out);
}